// Round 6
// baseline (1406.666 us; speedup 1.0000x reference)
//
#include <hip/hip_runtime.h>
#include <hip/hip_bf16.h>
#include <math.h>

// Problem constants
#define Bq   128
#define Tq   512
#define Iq   300   // input dim
#define Hq   150   // hidden per dir
#define G3   450   // 3*H
#define Kq   6
#define Cq   300
#define D2   300   // 2*H
#define THq  20
#define CLSq 5

typedef __attribute__((ext_vector_type(8))) short short8;     // 8 bf16 (4 VGPR) MFMA A/B frag
typedef __attribute__((ext_vector_type(4))) float floatx4;    // MFMA C/D frag

// ---------------------------------------------------------------------------
// Kernel 0: fp32 -> bf16 cast (RNE). n4 = n/4.
// ---------------------------------------------------------------------------
__global__ __launch_bounds__(256) void cast_bf16_kernel(
    const float* __restrict__ in, __hip_bfloat16* __restrict__ out, int n4)
{
    const int i = blockIdx.x * 256 + threadIdx.x;
    if (i < n4) {
        float4 v = *(const float4*)(in + 4 * (size_t)i);
        out[4 * (size_t)i + 0] = __float2bfloat16(v.x);
        out[4 * (size_t)i + 1] = __float2bfloat16(v.y);
        out[4 * (size_t)i + 2] = __float2bfloat16(v.z);
        out[4 * (size_t)i + 3] = __float2bfloat16(v.w);
    }
}

// ---------------------------------------------------------------------------
// Kernel 1: gi GEMM via bf16 MFMA 16x16x32 (verified layouts, R6-proven).
// ---------------------------------------------------------------------------
#define LB 40

__global__ __launch_bounds__(256) void gi_gemm_mfma(
    const __hip_bfloat16* __restrict__ xb,    // [B][T][300] bf16
    const __hip_bfloat16* __restrict__ Wbf,   // [2][450][300] bf16
    const float* __restrict__ bf_, const float* __restrict__ bb_,
    float* __restrict__ gic, int t0f, int t0b, int tcShift)
{
    const int dir = blockIdx.z;
    const unsigned short* W = (const unsigned short*)(Wbf + (size_t)dir * G3 * Iq);
    const unsigned short* X = (const unsigned short*)xb;
    const float* bias = dir ? bb_ : bf_;
    const int t0 = dir ? t0b : t0f;
    const int TCr = 1 << tcShift;
    float* outb = gic + (size_t)dir * Bq * TCr * G3;

    const int m0 = blockIdx.y * 128;
    const int n0 = blockIdx.x * 128;
    const int tid  = threadIdx.x;
    const int wv   = tid >> 6, lane = tid & 63;
    const int wm   = wv & 1,  wn   = wv >> 1;
    const int quad = lane >> 4, mr = lane & 15;

    __shared__ __align__(16) unsigned short Ab[128 * LB];
    __shared__ __align__(16) unsigned short Bb[128 * LB];

    floatx4 acc[4][4];
    #pragma unroll
    for (int i = 0; i < 4; ++i)
        #pragma unroll
        for (int j = 0; j < 4; ++j)
            acc[i][j] = (floatx4){0.f, 0.f, 0.f, 0.f};

    for (int k0 = 0; k0 < 320; k0 += 32) {
        __syncthreads();
        #pragma unroll
        for (int i = 0; i < 4; ++i) {
            const int g = tid + 256 * i;         // 0..1023
            const int row = g >> 3, kq = g & 7;  // 4-bf16 granule
            const int k = k0 + kq * 4;
            const int r = m0 + row;
            const int bb2 = r >> tcShift, lt = r & (TCr - 1);
            ushort4 av = make_ushort4(0, 0, 0, 0);
            if (k < Iq)
                av = *(const ushort4*)(X + ((size_t)bb2 * Tq + t0 + lt) * Iq + k);
            *(ushort4*)&Ab[row * LB + kq * 4] = av;
            const int n = n0 + row;
            ushort4 bv = make_ushort4(0, 0, 0, 0);
            if (n < G3 && k < Iq)
                bv = *(const ushort4*)(W + (size_t)n * Iq + k);
            *(ushort4*)&Bb[row * LB + kq * 4] = bv;
        }
        __syncthreads();

        short8 af[4], bfr[4];
        #pragma unroll
        for (int i = 0; i < 4; ++i)
            af[i] = *(const short8*)&Ab[(wm * 64 + i * 16 + mr) * LB + quad * 8];
        #pragma unroll
        for (int j = 0; j < 4; ++j)
            bfr[j] = *(const short8*)&Bb[(wn * 64 + j * 16 + mr) * LB + quad * 8];
        #pragma unroll
        for (int i = 0; i < 4; ++i)
            #pragma unroll
            for (int j = 0; j < 4; ++j)
                acc[i][j] = __builtin_amdgcn_mfma_f32_16x16x32_bf16(
                    af[i], bfr[j], acc[i][j], 0, 0, 0);
    }

    #pragma unroll
    for (int j = 0; j < 4; ++j) {
        const int gn = n0 + wn * 64 + j * 16 + mr;
        if (gn >= G3) continue;
        const float bv = bias[gn];
        #pragma unroll
        for (int i = 0; i < 4; ++i) {
            const int mbase = m0 + wm * 64 + i * 16 + quad * 4;
            #pragma unroll
            for (int rg = 0; rg < 4; ++rg)
                outb[(size_t)(mbase + rg) * G3 + gn] = acc[i][j][rg] + bv;
        }
    }
}

// ---------------------------------------------------------------------------
// Kernel 2: GRU recurrence, HALF-row-per-lane (R13).
// R7-R12 post-mortem: the allocator tops out at <=128 VGPRs for this kernel
// no matter what (120/96/112/112/128 across launch-bound, waves_per_eu, and
// LDS-pad variants). Full-row (152 regs) can never be resident. So lower
// the DEMAND below the empirical cap instead: 1024 threads, lane =
// (row = tid>>1, p = tid&1); each lane owns HALF a Whh row = 75 weights
// (19 named float4s ~= 76 VGPRs; total demand ~105 < 128 cap).
//  - half-dot over h-half p, then ONE DPP quad-perm lane^1 swap (register
//    pipe, R8-proven correct) gives both pair lanes the full row sum.
//  - h lives in 2 half-copies (76-float stride, float4-aligned); a wave's
//    lanes split 2-way between the copies -> 2-way broadcast reads = free.
//  - gi/bhh folded by the p==0 lane pre-reduce; n-rows' p==0 lanes fuse the
//    gate (their prefetched gi IS gi_n); 2 barriers/step; LDS history flush.
//  - stage[] padded so LDS > 80 KB: with 1024 threads 2 blocks/CU would
//    otherwise fit -> 8 waves/SIMD -> 64-VGPR pressure target -> weights
//    sunk again. >80 KB forces 1 block/CU (grid is 1/CU anyway).
// ---------------------------------------------------------------------------
template<int CTRL>
__device__ __forceinline__ float qadd(float v) {
    return v + __int_as_float(__builtin_amdgcn_update_dpp(
        0, __float_as_int(v), CTRL, 0xF, 0xF, true));
}

__global__
__attribute__((amdgpu_flat_work_group_size(1024, 1024)))
__attribute__((amdgpu_waves_per_eu(4, 4)))
void gru_rec(
    const float* __restrict__ gic,     // [2][B][TCr][450]
    const float* __restrict__ Whh_f, const float* __restrict__ bhh_f,
    const float* __restrict__ Whh_b, const float* __restrict__ bhh_b,
    float* __restrict__ hstate,        // [2][B][150]
    float* __restrict__ seq,           // [B][T][300]
    int chunk, int tcShift)
{
    const int TCr = 1 << tcShift;
    const int bid = blockIdx.x;
    const int dir = bid & 1;
    const int b   = bid >> 1;
    const float* Whh = dir ? Whh_b : Whh_f;
    const float* bhh = dir ? bhh_b : bhh_f;
    const int tid = threadIdx.x;
    const int row = tid >> 1;              // Whh row (valid < 450)
    const int p   = tid & 1;               // h-half
    const bool gemv = (row < G3);
    const bool lead = gemv && (p == 0);    // pair leader
    const bool gate = lead && (row >= 300);// n-row leaders also do gates
    const int t = row - 300;               // gate row (valid when gate)

    // LDS pad: total > 80 KB -> 1 block/CU -> 4 waves/SIMD -> 128-VGPR target
    __shared__ __align__(16) float stage[140 * 150];
    __shared__ __align__(16) float hbufX[2 * 76];    // h half-copies, slot 75 = pad 0
    __shared__ float sArr[300];                      // r/z pre-activations

    // weight base: this lane's half-row (inactive lanes -> row 0, unused)
    const float* wr = Whh + (size_t)(gemv ? row : 0) * Hq + p * 75;

    // 19 NAMED float4 weights (~76 VGPRs; no array -> no scratch).
    // Half-row base alignment is only 4B (75*4=300B odd granule) -> scalar
    // loads, one-time cost outside the loop.
    float4 w0,  w1,  w2,  w3,  w4,  w5,  w6,  w7,  w8,  w9;
    float4 w10, w11, w12, w13, w14, w15, w16, w17, w18;
#define WLD(i) w##i = make_float4(wr[4*(i)], wr[4*(i)+1], wr[4*(i)+2], wr[4*(i)+3]);
    WLD(0)  WLD(1)  WLD(2)  WLD(3)  WLD(4)  WLD(5)  WLD(6)  WLD(7)
    WLD(8)  WLD(9)  WLD(10) WLD(11) WLD(12) WLD(13) WLD(14) WLD(15)
    WLD(16) WLD(17)
#undef WLD
    w18 = make_float4(wr[72], wr[73], wr[74], 0.f);  // cols 72..74 of the half

    const float bh = lead ? bhh[row] : 0.f;

    float* hs = hstate + (size_t)(dir * Bq + b) * Hq;
    float hprev = 0.f;
    if (gate && chunk > 0) hprev = hs[t];

    // init h half-copies (slot 75 of each stays 0 forever)
    if (tid < 152) {
        const int cp = (tid >= 76) ? 1 : 0;
        const int slot = tid - 76 * cp;
        const int j = cp * 75 + slot;
        hbufX[tid] = (slot < 75 && chunk > 0) ? hs[j] : 0.f;
    }
    __syncthreads();

    const float* gib = gic + (size_t)(dir * Bq + b) * TCr * G3;
    const int t0 = dir ? (Tq - TCr * (chunk + 1)) : (chunk * TCr);
    float* seqb = seq + (size_t)b * Tq * D2 + dir * Hq;
    const float4* hb = (const float4*)hbufX + p * 19;   // this half's 19 float4s

    const int lt0 = dir ? (TCr - 1) : 0;
    float gval = lead ? gib[(size_t)lt0 * G3 + row] : 0.f;

    for (int s = 0; s < TCr; ++s) {
        const int ltn = dir ? (TCr - 2 - s) : (s + 1);
        float gnext = 0.f;
        if (s + 1 < TCr && lead)
            gnext = gib[(size_t)ltn * G3 + row];

        // half-dot: 19 stanzas, 3 independent accumulators
        // leader folds bias + gi (r/z rows); n-rows fold bias only (gi_n
        // stays in gval for the gate's tanh argument)
        float a0 = lead ? (bh + ((row < 300) ? gval : 0.f)) : 0.f;
        float a1 = 0.f, a2 = 0.f;
#define ST(i, A) { const float4 hv = hb[i];                           \
                   A += hv.x * w##i.x + hv.y * w##i.y                 \
                      + hv.z * w##i.z + hv.w * w##i.w; }
        ST(0,a0)  ST(1,a1)  ST(2,a2)
        ST(3,a0)  ST(4,a1)  ST(5,a2)
        ST(6,a0)  ST(7,a1)  ST(8,a2)
        ST(9,a0)  ST(10,a1) ST(11,a2)
        ST(12,a0) ST(13,a1) ST(14,a2)
        ST(15,a0) ST(16,a1) ST(17,a2)
        ST(18,a0)
#undef ST
        float acc = a0 + (a1 + a2);
        // pair combine: lane^1 quad-perm swap -> both lanes get full sum
        acc = qadd<0xB1>(acc);

        float ghn = 0.f;
        if (lead) {
            if (row < 300) sArr[row] = acc;
            else           ghn = acc;          // includes bhh_n
        }
        __syncthreads();

        if (gate) {
            const float r  = 1.f / (1.f + __expf(-sArr[t]));
            const float z  = 1.f / (1.f + __expf(-sArr[150 + t]));
            const float nv = tanhf(gval + r * ghn);   // gval == gi_n[t]
            const float hn = (1.f - z) * nv + z * hprev;
            hprev = hn;
            const int cp = (t >= 75) ? 1 : 0;
            hbufX[cp * 76 + (t - 75 * cp)] = hn;
            stage[(s & 63) * 150 + t] = hn;   // LDS history, no global store
        }
        __syncthreads();

        // periodic cooperative flush of the h history
        if ((s & 63) == 63 || s == TCr - 1) {
            const int sf0 = s & ~63;
            const int nf2 = (s - sf0 + 1) * 75;        // float2 count
            for (int idx = tid; idx < nf2; idx += 1024) {
                const int rrow = idx / 75, cc = idx % 75;
                const int ss = sf0 + rrow;
                const int ltw = dir ? (TCr - 1 - ss) : ss;
                *(float2*)(seqb + (size_t)(t0 + ltw) * D2 + 2 * cc) =
                    *(const float2*)&stage[rrow * 150 + 2 * cc];
            }
        }

        gval = gnext;
    }

    if (gate) hs[t] = hprev;
}

// ---------------------------------------------------------------------------
// Kernel 3a: ctxW[k][d] = battn[k][d] + sum_c attn_context[k][c]*Wattn[k][c][d]
// ---------------------------------------------------------------------------
__global__ void ctxw_kernel(
    const float* __restrict__ attn_context,
    const float* __restrict__ Wattn,
    const float* __restrict__ battn,
    float* __restrict__ ctxW)
{
    const int o = blockIdx.x * 256 + threadIdx.x;
    if (o >= Kq * D2) return;
    const int k = o / D2, d = o % D2;
    float acc = battn[o];
    const float* Wp = Wattn + ((size_t)k * (Cq + D2)) * D2 + d;
    for (int c = 0; c < Cq; ++c)
        acc += attn_context[k * Cq + c] * Wp[(size_t)c * D2];
    ctxW[o] = acc;
}

// ---------------------------------------------------------------------------
// Kernel 3b: context[b][k][:] = tanh(ctxW[k] + hidden[b] @ Wattn[k,300:,:])
// ---------------------------------------------------------------------------
__global__ __launch_bounds__(256) void ctx_compute(
    const float* __restrict__ seq,
    const float* __restrict__ Wattn,
    const float* __restrict__ ctxW,
    float* __restrict__ context,      // [B][6][300]
    float* __restrict__ normsq)       // [B][6]
{
    const int b = blockIdx.x;
    const int k = blockIdx.y;
    const int tid = threadIdx.x;
    const int lane = tid & 63, wv = tid >> 6;

    __shared__ float hb[304];
    __shared__ float red[4];

    for (int i = tid; i < D2; i += 256)
        hb[i] = (i < Hq) ? seq[((size_t)b * Tq + (Tq - 1)) * D2 + i]
                         : seq[(size_t)b * Tq * D2 + i];
    __syncthreads();

    float ssq = 0.f;
    for (int d = tid; d < D2; d += 256) {
        float acc = ctxW[k * D2 + d];
        const float* Wp = Wattn + ((size_t)k * (Cq + D2) + Cq) * D2 + d;
        for (int jj = 0; jj < D2; ++jj)
            acc += hb[jj] * Wp[(size_t)jj * D2];
        const float c = tanhf(acc);
        context[((size_t)b * Kq + k) * D2 + d] = c;
        ssq += c * c;
    }
    for (int off = 32; off > 0; off >>= 1) ssq += __shfl_xor(ssq, off, 64);
    if (lane == 0) red[wv] = ssq;
    __syncthreads();
    if (tid == 0) normsq[b * Kq + k] = red[0] + red[1] + red[2] + red[3];
}

// ---------------------------------------------------------------------------
// Kernel 3c: gram regularizer per b
// ---------------------------------------------------------------------------
__global__ __launch_bounds__(256) void gram_kernel(
    const float* __restrict__ context,
    const float* __restrict__ normsq,
    float* __restrict__ regbuf)
{
    const int b = blockIdx.x;
    const int tid = threadIdx.x;
    __shared__ float ctx[Kq * D2];
    __shared__ float Gm[36];

    for (int o = tid; o < Kq * D2; o += 256)
        ctx[o] = context[(size_t)b * Kq * D2 + o];
    __syncthreads();

    if (tid < 36) {
        const int k = tid / 6, jj = tid % 6;
        float g = 0.f;
        for (int d = 0; d < D2; ++d)
            g += ctx[k * D2 + d] * ctx[jj * D2 + d];
        const float nk = fmaxf(sqrtf(normsq[b * Kq + k]), 1e-12f);
        const float nj = fmaxf(sqrtf(normsq[b * Kq + jj]), 1e-12f);
        g /= (nk * nj);
        const float diff = g - ((k == jj) ? 1.f : 0.f);
        Gm[tid] = diff * diff;
    }
    __syncthreads();
    if (tid == 0) {
        float s = 0.f;
        for (int i = 0; i < 36; ++i) s += Gm[i];
        regbuf[b] = sqrtf(s);
    }
}

// ---------------------------------------------------------------------------
// Kernel 4a: energy[b][t][k] = seq[b][t] . context[b][k]   grid (8, B)
// ---------------------------------------------------------------------------
__global__ __launch_bounds__(256) void energy_kernel(
    const float* __restrict__ seq,
    const float* __restrict__ context,
    float* __restrict__ en)           // [B][512][6]
{
    const int tc = blockIdx.x;
    const int b  = blockIdx.y;
    const int tid = threadIdx.x;
    const int lane = tid & 63, wv = tid >> 6;

    __shared__ float ctx[Kq * D2];
    for (int o = tid; o < Kq * D2; o += 256)
        ctx[o] = context[(size_t)b * Kq * D2 + o];
    __syncthreads();

    const float* seqb = seq + (size_t)b * Tq * D2;
    for (int s = 0; s < 16; ++s) {
        const int tt = tc * 64 + s * 4 + wv;
        float acc[Kq] = {0.f,0.f,0.f,0.f,0.f,0.f};
        for (int d = lane; d < D2; d += 64) {
            const float sv = seqb[(size_t)tt * D2 + d];
            #pragma unroll
            for (int k = 0; k < Kq; ++k) acc[k] += sv * ctx[k * D2 + d];
        }
        #pragma unroll
        for (int k = 0; k < Kq; ++k) {
            float v = acc[k];
            for (int off = 32; off > 0; off >>= 1) v += __shfl_xor(v, off, 64);
            if (lane == 0) en[((size_t)b * Tq + tt) * Kq + k] = v;
        }
    }
}

// ---------------------------------------------------------------------------
// Kernel 4b: softmax over t per (b,k), in-place on en.  grid (B)
// ---------------------------------------------------------------------------
__global__ __launch_bounds__(256) void softmax_kernel(float* __restrict__ en)
{
    const int b = blockIdx.x;
    const int tid = threadIdx.x;
    const int lane = tid & 63, wv = tid >> 6;
    __shared__ float es[Tq * Kq];
    __shared__ float red[8];

    for (int o = tid; o < Tq * Kq; o += 256)
        es[o] = en[(size_t)b * Tq * Kq + o];
    __syncthreads();

    for (int k = 0; k < Kq; ++k) {
        float m = -1e30f;
        for (int tt = tid; tt < Tq; tt += 256) m = fmaxf(m, es[tt * Kq + k]);
        for (int off = 32; off > 0; off >>= 1) m = fmaxf(m, __shfl_xor(m, off, 64));
        if (lane == 0) red[wv] = m;
        __syncthreads();
        m = fmaxf(fmaxf(red[0], red[1]), fmaxf(red[2], red[3]));
        float ssum = 0.f;
        for (int tt = tid; tt < Tq; tt += 256) {
            const float e = __expf(es[tt * Kq + k] - m);
            es[tt * Kq + k] = e;
            ssum += e;
        }
        for (int off = 32; off > 0; off >>= 1) ssum += __shfl_xor(ssum, off, 64);
        if (lane == 0) red[4 + wv] = ssum;
        __syncthreads();
        const float inv = 1.f / (red[4] + red[5] + red[6] + red[7]);
        for (int tt = tid; tt < Tq; tt += 256) es[tt * Kq + k] *= inv;
        __syncthreads();
    }

    for (int o = tid; o < Tq * Kq; o += 256)
        en[(size_t)b * Tq * Kq + o] = es[o];
}

// ---------------------------------------------------------------------------
// Kernel 4c: pooled partials over 64-t chunks.  grid (8, B)
// ---------------------------------------------------------------------------
__global__ __launch_bounds__(256) void pooledp_kernel(
    const float* __restrict__ seq,
    const float* __restrict__ en,     // probs now
    float* __restrict__ partial)      // [B*8][1800]
{
    const int tc = blockIdx.x;
    const int b  = blockIdx.y;
    const int tid = threadIdx.x;
    const int lane = tid & 63, wv = tid >> 6;

    __shared__ float pr[64 * Kq];
    __shared__ float part[4][Kq * D2];   // 28.8 KB

    if (tid < 64 * Kq / 2) {
        pr[tid]       = en[((size_t)b * Tq + tc * 64) * Kq + tid];
        pr[tid + 192] = en[((size_t)b * Tq + tc * 64) * Kq + tid + 192];
    }
    __syncthreads();

    const float* seqb = seq + (size_t)b * Tq * D2;

    float pp[Kq][5];
    #pragma unroll
    for (int k = 0; k < Kq; ++k)
        #pragma unroll
        for (int q = 0; q < 5; ++q) pp[k][q] = 0.f;

    for (int s = 0; s < 16; ++s) {
        const int tl = s * 4 + wv;
        const int tt = tc * 64 + tl;
        float prr[Kq];
        #pragma unroll
        for (int k = 0; k < Kq; ++k) prr[k] = pr[tl * Kq + k];
        #pragma unroll
        for (int q = 0; q < 5; ++q) {
            const int d = lane + q * 64;
            const float sv = (d < D2) ? seqb[(size_t)tt * D2 + d] : 0.f;
            #pragma unroll
            for (int k = 0; k < Kq; ++k) pp[k][q] += prr[k] * sv;
        }
    }
    #pragma unroll
    for (int k = 0; k < Kq; ++k)
        #pragma unroll
        for (int q = 0; q < 5; ++q) {
            const int d = lane + q * 64;
            if (d < D2) part[wv][k * D2 + d] = pp[k][q];
        }
    __syncthreads();
    float* op = partial + ((size_t)b * 8 + tc) * (Kq * D2);
    for (int o = tid; o < Kq * D2; o += 256)
        op[o] = part[0][o] + part[1][o] + part[2][o] + part[3][o];
}

// ---------------------------------------------------------------------------
// Kernel 4d: final: pooled reduce -> topic -> logits -> softmax.  grid (B)
// ---------------------------------------------------------------------------
__global__ __launch_bounds__(256) void final_kernel(
    const float* __restrict__ partial,
    const float* __restrict__ Wtop,
    const float* __restrict__ btop,
    const float* __restrict__ Wout,
    const float* __restrict__ bout,
    float* __restrict__ outp)
{
    const int b = blockIdx.x;
    const int tid = threadIdx.x;
    __shared__ float pooled[Kq * D2];
    __shared__ float feats[Kq * THq];
    __shared__ float lsm[8];

    for (int o = tid; o < Kq * D2; o += 256) {
        float s = 0.f;
        #pragma unroll
        for (int c = 0; c < 8; ++c)
            s += partial[((size_t)b * 8 + c) * (Kq * D2) + o];
        pooled[o] = s;
    }
    __syncthreads();

    if (tid < Kq * THq) {
        const int k = tid / THq, hh = tid % THq;
        float acc = btop[tid];
        const float* wp = Wtop + (size_t)k * D2 * THq + hh;
        for (int d = 0; d < D2; ++d)
            acc += pooled[k * D2 + d] * wp[(size_t)d * THq];
        feats[tid] = fmaxf(acc, 0.f);
    }
    __syncthreads();

    if (tid < CLSq) {
        float acc = bout[tid];
        for (int f = 0; f < Kq * THq; ++f)
            acc += feats[f] * Wout[f * CLSq + tid];
        lsm[tid] = acc;
    }
    __syncthreads();
    if (tid < CLSq) {
        float m = lsm[0];
        for (int c = 1; c < CLSq; ++c) m = fmaxf(m, lsm[c]);
        float s = 0.f;
        for (int c = 0; c < CLSq; ++c) s += __expf(lsm[c] - m);
        outp[(size_t)b * CLSq + tid] = __expf(lsm[tid] - m) / s;
    }
}

// ---------------------------------------------------------------------------
// Kernel 5: reg = mean_b regbuf[b]  -> d_out[640]
// ---------------------------------------------------------------------------
__global__ void reg_final(const float* __restrict__ regbuf, float* __restrict__ outp)
{
    const int tid = threadIdx.x;   // 128 threads
    float v = regbuf[tid];
    for (int off = 32; off > 0; off >>= 1) v += __shfl_xor(v, off, 64);
    __shared__ float r2[2];
    if ((tid & 63) == 0) r2[tid >> 6] = v;
    __syncthreads();
    if (tid == 0) outp[Bq * CLSq] = (r2[0] + r2[1]) * (1.f / (float)Bq);
}

// ---------------------------------------------------------------------------
extern "C" void kernel_launch(void* const* d_in, const int* in_sizes, int n_in,
                              void* d_out, int out_size, void* d_ws, size_t ws_size,
                              hipStream_t stream)
{
    const float* x     = (const float*)d_in[0];
    const float* Wih_f = (const float*)d_in[1];
    const float* Whh_f = (const float*)d_in[2];
    const float* bih_f = (const float*)d_in[3];
    const float* bhh_f = (const float*)d_in[4];
    const float* Wih_b = (const float*)d_in[5];
    const float* Whh_b = (const float*)d_in[6];
    const float* bih_b = (const float*)d_in[7];
    const float* bhh_b = (const float*)d_in[8];
    const float* attn_context = (const float*)d_in[9];
    const float* Wattn = (const float*)d_in[10];
    const float* battn = (const float*)d_in[11];
    const float* Wtop  = (const float*)d_in[12];
    const float* btop  = (const float*)d_in[13];
    const float* Wout  = (const float*)d_in[14];
    const float* bout  = (const float*)d_in[15];
    float* outp = (float*)d_out;

    // fixed workspace layout (float units)
    float* ws       = (float*)d_ws;
    float* seqv     = ws;                                   // 19,660,800
    float* hstate   = seqv + (size_t)Bq * Tq * D2;          // 38,400
    float* ctxW     = hstate + (size_t)2 * Bq * Hq;         // 1,800
    float* context  = ctxW + Kq * D2;                       // 230,400
    float* regbuf   = context + (size_t)Bq * Kq * D2;       // 128
    float* normsq   = regbuf + Bq;                          // 768
    float* en       = normsq + Bq * Kq;                     // 393,216
    float* partial  = en + (size_t)Bq * Tq * Kq;            // 1,843,200
    __hip_bfloat16* xb16 = (__hip_bfloat16*)(partial + (size_t)Bq * 8 * Kq * D2); // 19,660,800 bf16
    __hip_bfloat16* Wb16 = xb16 + (size_t)Bq * Tq * Iq;     // 270,000 bf16
    float* gi_chunk = (float*)(Wb16 + (size_t)2 * G3 * Iq); // 115200*TCr fp32
    const size_t fixed_floats = (size_t)(gi_chunk - ws);

    // pick largest TCr in {256,128,64,32} that fits ws_size
    int tcShift = 5;
    for (int sh = 8; sh >= 5; --sh) {
        size_t need = (fixed_floats + (size_t)115200 * (1 << sh)) * 4;
        if (need <= ws_size) { tcShift = sh; break; }
    }
    const int TCr = 1 << tcShift;
    const int NL = Tq / TCr;

    // one-time bf16 casts (x, Wih_f, Wih_b)
    cast_bf16_kernel<<<dim3((Bq * Tq * Iq / 4 + 255) / 256), 256, 0, stream>>>(
        x, xb16, Bq * Tq * Iq / 4);
    cast_bf16_kernel<<<dim3((G3 * Iq / 4 + 255) / 256), 256, 0, stream>>>(
        Wih_f, Wb16, G3 * Iq / 4);
    cast_bf16_kernel<<<dim3((G3 * Iq / 4 + 255) / 256), 256, 0, stream>>>(
        Wih_b, Wb16 + (size_t)G3 * Iq, G3 * Iq / 4);

    for (int c = 0; c < NL; ++c) {
        const int t0f = c * TCr;
        const int t0b = Tq - TCr * (c + 1);
        gi_gemm_mfma<<<dim3(4, Bq * TCr / 128, 2), 256, 0, stream>>>(
            xb16, Wb16, bih_f, bih_b, gi_chunk, t0f, t0b, tcShift);
        gru_rec<<<dim3(2 * Bq), 1024, 0, stream>>>(
            gi_chunk, Whh_f, bhh_f, Whh_b, bhh_b, hstate, seqv, c, tcShift);
    }

    ctxw_kernel<<<dim3((Kq * D2 + 255) / 256), 256, 0, stream>>>(
        attn_context, Wattn, battn, ctxW);
    ctx_compute<<<dim3(Bq, Kq), 256, 0, stream>>>(seqv, Wattn, ctxW, context, normsq);
    gram_kernel<<<dim3(Bq), 256, 0, stream>>>(context, normsq, regbuf);
    energy_kernel<<<dim3(8, Bq), 256, 0, stream>>>(seqv, context, en);
    softmax_kernel<<<dim3(Bq), 256, 0, stream>>>(en);
    pooledp_kernel<<<dim3(8, Bq), 256, 0, stream>>>(seqv, en, partial);
    final_kernel<<<dim3(Bq), 256, 0, stream>>>(partial, Wtop, btop, Wout, bout, outp);
    reg_final<<<dim3(1), 128, 0, stream>>>(regbuf, outp);
}

// Round 7
// 1114.164 us; speedup vs baseline: 1.2625x; 1.2625x over previous
//
#include <hip/hip_runtime.h>
#include <hip/hip_bf16.h>
#include <math.h>

// Problem constants
#define Bq   128
#define Tq   512
#define Iq   300   // input dim
#define Hq   150   // hidden per dir
#define G3   450   // 3*H
#define Kq   6
#define Cq   300
#define D2   300   // 2*H
#define THq  20
#define CLSq 5

typedef __attribute__((ext_vector_type(8))) short short8;     // 8 bf16 (4 VGPR) MFMA A/B frag
typedef __attribute__((ext_vector_type(4))) float floatx4;    // MFMA C/D frag
typedef _Float16 h2v __attribute__((ext_vector_type(2)));     // packed half pair

// ---------------------------------------------------------------------------
// Kernel 0: fp32 -> bf16 cast (RNE). n4 = n/4.
// ---------------------------------------------------------------------------
__global__ __launch_bounds__(256) void cast_bf16_kernel(
    const float* __restrict__ in, __hip_bfloat16* __restrict__ out, int n4)
{
    const int i = blockIdx.x * 256 + threadIdx.x;
    if (i < n4) {
        float4 v = *(const float4*)(in + 4 * (size_t)i);
        out[4 * (size_t)i + 0] = __float2bfloat16(v.x);
        out[4 * (size_t)i + 1] = __float2bfloat16(v.y);
        out[4 * (size_t)i + 2] = __float2bfloat16(v.z);
        out[4 * (size_t)i + 3] = __float2bfloat16(v.w);
    }
}

// ---------------------------------------------------------------------------
// Kernel 0b: Whh fp32 -> fp16, rows padded 150 -> 152 halves.
// out[dir][450][152]; cols >= 150 are 0.
// ---------------------------------------------------------------------------
__global__ __launch_bounds__(256) void cast_whh_f16(
    const float* __restrict__ Wf, const float* __restrict__ Wb,
    unsigned short* __restrict__ out)
{
    const int idx = blockIdx.x * 256 + threadIdx.x;     // one half per thread
    const int total = 2 * G3 * 152;
    if (idx >= total) return;
    const int dir = idx / (G3 * 152);
    const int rem = idx % (G3 * 152);
    const int r = rem / 152, c = rem % 152;
    float v = 0.f;
    if (c < Hq) v = (dir ? Wb : Wf)[(size_t)r * Hq + c];
    out[idx] = __builtin_bit_cast(unsigned short, (_Float16)v);
}

// ---------------------------------------------------------------------------
// Kernel 1: gi GEMM via bf16 MFMA 16x16x32 (verified layouts, R6-proven).
// ---------------------------------------------------------------------------
#define LB 40

__global__ __launch_bounds__(256) void gi_gemm_mfma(
    const __hip_bfloat16* __restrict__ xb,    // [B][T][300] bf16
    const __hip_bfloat16* __restrict__ Wbf,   // [2][450][300] bf16
    const float* __restrict__ bf_, const float* __restrict__ bb_,
    float* __restrict__ gic, int t0f, int t0b, int tcShift)
{
    const int dir = blockIdx.z;
    const unsigned short* W = (const unsigned short*)(Wbf + (size_t)dir * G3 * Iq);
    const unsigned short* X = (const unsigned short*)xb;
    const float* bias = dir ? bb_ : bf_;
    const int t0 = dir ? t0b : t0f;
    const int TCr = 1 << tcShift;
    float* outb = gic + (size_t)dir * Bq * TCr * G3;

    const int m0 = blockIdx.y * 128;
    const int n0 = blockIdx.x * 128;
    const int tid  = threadIdx.x;
    const int wv   = tid >> 6, lane = tid & 63;
    const int wm   = wv & 1,  wn   = wv >> 1;
    const int quad = lane >> 4, mr = lane & 15;

    __shared__ __align__(16) unsigned short Ab[128 * LB];
    __shared__ __align__(16) unsigned short Bb[128 * LB];

    floatx4 acc[4][4];
    #pragma unroll
    for (int i = 0; i < 4; ++i)
        #pragma unroll
        for (int j = 0; j < 4; ++j)
            acc[i][j] = (floatx4){0.f, 0.f, 0.f, 0.f};

    for (int k0 = 0; k0 < 320; k0 += 32) {
        __syncthreads();
        #pragma unroll
        for (int i = 0; i < 4; ++i) {
            const int g = tid + 256 * i;         // 0..1023
            const int row = g >> 3, kq = g & 7;  // 4-bf16 granule
            const int k = k0 + kq * 4;
            const int r = m0 + row;
            const int bb2 = r >> tcShift, lt = r & (TCr - 1);
            ushort4 av = make_ushort4(0, 0, 0, 0);
            if (k < Iq)
                av = *(const ushort4*)(X + ((size_t)bb2 * Tq + t0 + lt) * Iq + k);
            *(ushort4*)&Ab[row * LB + kq * 4] = av;
            const int n = n0 + row;
            ushort4 bv = make_ushort4(0, 0, 0, 0);
            if (n < G3 && k < Iq)
                bv = *(const ushort4*)(W + (size_t)n * Iq + k);
            *(ushort4*)&Bb[row * LB + kq * 4] = bv;
        }
        __syncthreads();

        short8 af[4], bfr[4];
        #pragma unroll
        for (int i = 0; i < 4; ++i)
            af[i] = *(const short8*)&Ab[(wm * 64 + i * 16 + mr) * LB + quad * 8];
        #pragma unroll
        for (int j = 0; j < 4; ++j)
            bfr[j] = *(const short8*)&Bb[(wn * 64 + j * 16 + mr) * LB + quad * 8];
        #pragma unroll
        for (int i = 0; i < 4; ++i)
            #pragma unroll
            for (int j = 0; j < 4; ++j)
                acc[i][j] = __builtin_amdgcn_mfma_f32_16x16x32_bf16(
                    af[i], bfr[j], acc[i][j], 0, 0, 0);
    }

    #pragma unroll
    for (int j = 0; j < 4; ++j) {
        const int gn = n0 + wn * 64 + j * 16 + mr;
        if (gn >= G3) continue;
        const float bv = bias[gn];
        #pragma unroll
        for (int i = 0; i < 4; ++i) {
            const int mbase = m0 + wm * 64 + i * 16 + quad * 4;
            #pragma unroll
            for (int rg = 0; rg < 4; ++rg)
                outb[(size_t)(mbase + rg) * G3 + gn] = acc[i][j][rg] + bv;
        }
    }
}

// ---------------------------------------------------------------------------
// Kernel 2: GRU recurrence, fp16 weights resident in LDS (R14).
// R7-R13 post-mortem: register-resident weights are unobtainable on this
// toolchain (6 attempts, VGPR grant capped 64-128) -> every prior version
// re-read ~270KB of Whh from L2 per block per step. Aggregate 256 blocks x
// 270KB/step = 69MB/step / 34.5 TB/s L2 ceiling = 2.0us/step — exactly the
// measured 457-504us/256steps. The GRU was aggregate-L2-BW-bound all along.
// Fix: Whh lives in LDS as fp16 (450 rows x 152 halves = 136.8 KB <= 160),
// staged once per launch. fp16 (10-bit mantissa) is MORE precise than the
// bf16 already used for gi; fp32 accumulate via v_dot2_f32_f16.
//  - lane r < 450 owns full row r: 19 ds_read_b128/step, row stride 304B
//    (lanes 0-7 tile all 32 banks exactly -> conflict-free, pure BW).
//    LDS floor: 136.8KB / 128B/cyc = 1069 cyc/step vs 4800 at L2.
//  - h kept packed-fp16 in LDS (h2b, 76 dwords), broadcast uint4 reads.
//  - gi/bhh folded; n-lanes (300..449) fuse the gate; h written per step
//    straight to seq (600B coalesced) — stage[] dropped (LDS is full).
//  - dot2 guarded by __has_builtin with scalar-unpack fallback.
// ---------------------------------------------------------------------------
__device__ __forceinline__ float dot2h(unsigned int w, unsigned int h, float c)
{
#if __has_builtin(__builtin_amdgcn_fdot2)
    return __builtin_amdgcn_fdot2(__builtin_bit_cast(h2v, w),
                                  __builtin_bit_cast(h2v, h), c, false);
#else
    const h2v a = __builtin_bit_cast(h2v, w);
    const h2v b = __builtin_bit_cast(h2v, h);
    return c + (float)a.x * (float)b.x + (float)a.y * (float)b.y;
#endif
}

__global__ __launch_bounds__(512) void gru_rec(
    const float* __restrict__ gic,            // [2][B][TCr][450]
    const unsigned short* __restrict__ W16,   // [2][450][152] fp16
    const float* __restrict__ bhh_f, const float* __restrict__ bhh_b,
    float* __restrict__ hstate,               // [2][B][150]
    float* __restrict__ seq,                  // [B][T][300]
    int chunk, int tcShift)
{
    const int TCr = 1 << tcShift;
    const int bid = blockIdx.x;
    const int dir = bid & 1;
    const int b   = bid >> 1;
    const float* bhh = dir ? bhh_b : bhh_f;
    const int tid = threadIdx.x;
    const int row = tid;                        // Whh row (valid < 450)
    const bool gemv = (row < G3);
    const bool gate = (row >= 300 && row < G3); // n-row lanes also do gates
    const int t = row - 300;                    // gate row (valid when gate)

    __shared__ __align__(16) unsigned int Wlds[G3 * 76]; // [450][76] dw = 136.8 KB
    __shared__ __align__(16) unsigned int h2b[80];       // h as 76 packed half2
    __shared__ float sArr[300];                          // r/z pre-activations

    // ---- stage W(dir) into LDS: 8550 uint4, fully coalesced, one-time ----
    {
        const uint4* Wg = (const uint4*)(W16 + (size_t)dir * G3 * 152);
        uint4* Wl = (uint4*)Wlds;
        for (int i = tid; i < G3 * 19; i += 512) Wl[i] = Wg[i];
    }

    const float bh = gemv ? bhh[row] : 0.f;

    float* hs = hstate + (size_t)(dir * Bq + b) * Hq;
    float hprev = 0.f;
    if (gate && chunk > 0) hprev = hs[t];

    // ---- init packed h (pairs 75..79 stay 0) ----
    if (tid < 80) {
        unsigned int v = 0;
        if (tid < 76 && chunk > 0) {
            const float lo = (2 * tid     < Hq) ? hs[2 * tid]     : 0.f;
            const float hi = (2 * tid + 1 < Hq) ? hs[2 * tid + 1] : 0.f;
            h2v p; p.x = (_Float16)lo; p.y = (_Float16)hi;
            v = __builtin_bit_cast(unsigned int, p);
        }
        h2b[tid] = v;
    }
    __syncthreads();

    const float* gib = gic + (size_t)(dir * Bq + b) * TCr * G3;
    const int t0 = dir ? (Tq - TCr * (chunk + 1)) : (chunk * TCr);
    float* seqb = seq + (size_t)b * Tq * D2 + dir * Hq;

    const uint4* wr4 = (const uint4*)(Wlds + row * 76);  // this row's 19 chunks
    const uint4* h4  = (const uint4*)h2b;                // 19 broadcast chunks

    int lt = dir ? (TCr - 1) : 0;
    float gval = gemv ? gib[(size_t)lt * G3 + row] : 0.f;

    for (int s = 0; s < TCr; ++s) {
        const int ltn = dir ? (TCr - 2 - s) : (s + 1);
        float gnext = 0.f;
        if (s + 1 < TCr && gemv)
            gnext = gib[(size_t)ltn * G3 + row];

        float ghn = 0.f;                      // n-row pre-activation
        if (gemv) {
            float a0 = bh + ((row < 300) ? gval : 0.f);
            float a1 = 0.f, a2 = 0.f, a3 = 0.f;
            #pragma unroll
            for (int j = 0; j < 19; ++j) {
                const uint4 w = wr4[j];       // ds_read_b128, conflict-free
                const uint4 h = h4[j];        // broadcast
                a0 = dot2h(w.x, h.x, a0);
                a1 = dot2h(w.y, h.y, a1);
                a2 = dot2h(w.z, h.z, a2);
                a3 = dot2h(w.w, h.w, a3);
            }
            const float acc = (a0 + a1) + (a2 + a3);
            if (row < 300) sArr[row] = acc;
            else           ghn = acc;         // includes bhh_n
        }
        __syncthreads();

        if (gate) {
            const float r  = 1.f / (1.f + __expf(-sArr[t]));
            const float z  = 1.f / (1.f + __expf(-sArr[150 + t]));
            const float nv = tanhf(gval + r * ghn);   // gval == gi_n[t]
            const float hn = (1.f - z) * nv + z * hprev;
            hprev = hn;
            ((_Float16*)h2b)[t] = (_Float16)hn;       // ds_write_b16
            seqb[(size_t)(t0 + lt) * D2 + t] = hn;    // 600B coalesced store
        }
        __syncthreads();

        gval = gnext;
        lt = ltn;
    }

    if (gate) hs[t] = hprev;
}

// ---------------------------------------------------------------------------
// Kernel 3a: ctxW[k][d] = battn[k][d] + sum_c attn_context[k][c]*Wattn[k][c][d]
// ---------------------------------------------------------------------------
__global__ void ctxw_kernel(
    const float* __restrict__ attn_context,
    const float* __restrict__ Wattn,
    const float* __restrict__ battn,
    float* __restrict__ ctxW)
{
    const int o = blockIdx.x * 256 + threadIdx.x;
    if (o >= Kq * D2) return;
    const int k = o / D2, d = o % D2;
    float acc = battn[o];
    const float* Wp = Wattn + ((size_t)k * (Cq + D2)) * D2 + d;
    for (int c = 0; c < Cq; ++c)
        acc += attn_context[k * Cq + c] * Wp[(size_t)c * D2];
    ctxW[o] = acc;
}

// ---------------------------------------------------------------------------
// Kernel 3b: context[b][k][:] = tanh(ctxW[k] + hidden[b] @ Wattn[k,300:,:])
// ---------------------------------------------------------------------------
__global__ __launch_bounds__(256) void ctx_compute(
    const float* __restrict__ seq,
    const float* __restrict__ Wattn,
    const float* __restrict__ ctxW,
    float* __restrict__ context,      // [B][6][300]
    float* __restrict__ normsq)       // [B][6]
{
    const int b = blockIdx.x;
    const int k = blockIdx.y;
    const int tid = threadIdx.x;
    const int lane = tid & 63, wv = tid >> 6;

    __shared__ float hb[304];
    __shared__ float red[4];

    for (int i = tid; i < D2; i += 256)
        hb[i] = (i < Hq) ? seq[((size_t)b * Tq + (Tq - 1)) * D2 + i]
                         : seq[(size_t)b * Tq * D2 + i];
    __syncthreads();

    float ssq = 0.f;
    for (int d = tid; d < D2; d += 256) {
        float acc = ctxW[k * D2 + d];
        const float* Wp = Wattn + ((size_t)k * (Cq + D2) + Cq) * D2 + d;
        for (int jj = 0; jj < D2; ++jj)
            acc += hb[jj] * Wp[(size_t)jj * D2];
        const float c = tanhf(acc);
        context[((size_t)b * Kq + k) * D2 + d] = c;
        ssq += c * c;
    }
    for (int off = 32; off > 0; off >>= 1) ssq += __shfl_xor(ssq, off, 64);
    if (lane == 0) red[wv] = ssq;
    __syncthreads();
    if (tid == 0) normsq[b * Kq + k] = red[0] + red[1] + red[2] + red[3];
}

// ---------------------------------------------------------------------------
// Kernel 3c: gram regularizer per b
// ---------------------------------------------------------------------------
__global__ __launch_bounds__(256) void gram_kernel(
    const float* __restrict__ context,
    const float* __restrict__ normsq,
    float* __restrict__ regbuf)
{
    const int b = blockIdx.x;
    const int tid = threadIdx.x;
    __shared__ float ctx[Kq * D2];
    __shared__ float Gm[36];

    for (int o = tid; o < Kq * D2; o += 256)
        ctx[o] = context[(size_t)b * Kq * D2 + o];
    __syncthreads();

    if (tid < 36) {
        const int k = tid / 6, jj = tid % 6;
        float g = 0.f;
        for (int d = 0; d < D2; ++d)
            g += ctx[k * D2 + d] * ctx[jj * D2 + d];
        const float nk = fmaxf(sqrtf(normsq[b * Kq + k]), 1e-12f);
        const float nj = fmaxf(sqrtf(normsq[b * Kq + jj]), 1e-12f);
        g /= (nk * nj);
        const float diff = g - ((k == jj) ? 1.f : 0.f);
        Gm[tid] = diff * diff;
    }
    __syncthreads();
    if (tid == 0) {
        float s = 0.f;
        for (int i = 0; i < 36; ++i) s += Gm[i];
        regbuf[b] = sqrtf(s);
    }
}

// ---------------------------------------------------------------------------
// Kernel 4a: energy[b][t][k] = seq[b][t] . context[b][k]   grid (8, B)
// ---------------------------------------------------------------------------
__global__ __launch_bounds__(256) void energy_kernel(
    const float* __restrict__ seq,
    const float* __restrict__ context,
    float* __restrict__ en)           // [B][512][6]
{
    const int tc = blockIdx.x;
    const int b  = blockIdx.y;
    const int tid = threadIdx.x;
    const int lane = tid & 63, wv = tid >> 6;

    __shared__ float ctx[Kq * D2];
    for (int o = tid; o < Kq * D2; o += 256)
        ctx[o] = context[(size_t)b * Kq * D2 + o];
    __syncthreads();

    const float* seqb = seq + (size_t)b * Tq * D2;
    for (int s = 0; s < 16; ++s) {
        const int tt = tc * 64 + s * 4 + wv;
        float acc[Kq] = {0.f,0.f,0.f,0.f,0.f,0.f};
        for (int d = lane; d < D2; d += 64) {
            const float sv = seqb[(size_t)tt * D2 + d];
            #pragma unroll
            for (int k = 0; k < Kq; ++k) acc[k] += sv * ctx[k * D2 + d];
        }
        #pragma unroll
        for (int k = 0; k < Kq; ++k) {
            float v = acc[k];
            for (int off = 32; off > 0; off >>= 1) v += __shfl_xor(v, off, 64);
            if (lane == 0) en[((size_t)b * Tq + tt) * Kq + k] = v;
        }
    }
}

// ---------------------------------------------------------------------------
// Kernel 4b: softmax over t per (b,k), in-place on en.  grid (B)
// ---------------------------------------------------------------------------
__global__ __launch_bounds__(256) void softmax_kernel(float* __restrict__ en)
{
    const int b = blockIdx.x;
    const int tid = threadIdx.x;
    const int lane = tid & 63, wv = tid >> 6;
    __shared__ float es[Tq * Kq];
    __shared__ float red[8];

    for (int o = tid; o < Tq * Kq; o += 256)
        es[o] = en[(size_t)b * Tq * Kq + o];
    __syncthreads();

    for (int k = 0; k < Kq; ++k) {
        float m = -1e30f;
        for (int tt = tid; tt < Tq; tt += 256) m = fmaxf(m, es[tt * Kq + k]);
        for (int off = 32; off > 0; off >>= 1) m = fmaxf(m, __shfl_xor(m, off, 64));
        if (lane == 0) red[wv] = m;
        __syncthreads();
        m = fmaxf(fmaxf(red[0], red[1]), fmaxf(red[2], red[3]));
        float ssum = 0.f;
        for (int tt = tid; tt < Tq; tt += 256) {
            const float e = __expf(es[tt * Kq + k] - m);
            es[tt * Kq + k] = e;
            ssum += e;
        }
        for (int off = 32; off > 0; off >>= 1) ssum += __shfl_xor(ssum, off, 64);
        if (lane == 0) red[4 + wv] = ssum;
        __syncthreads();
        const float inv = 1.f / (red[4] + red[5] + red[6] + red[7]);
        for (int tt = tid; tt < Tq; tt += 256) es[tt * Kq + k] *= inv;
        __syncthreads();
    }

    for (int o = tid; o < Tq * Kq; o += 256)
        en[(size_t)b * Tq * Kq + o] = es[o];
}

// ---------------------------------------------------------------------------
// Kernel 4c: pooled partials over 64-t chunks.  grid (8, B)
// ---------------------------------------------------------------------------
__global__ __launch_bounds__(256) void pooledp_kernel(
    const float* __restrict__ seq,
    const float* __restrict__ en,     // probs now
    float* __restrict__ partial)      // [B*8][1800]
{
    const int tc = blockIdx.x;
    const int b  = blockIdx.y;
    const int tid = threadIdx.x;
    const int lane = tid & 63, wv = tid >> 6;

    __shared__ float pr[64 * Kq];
    __shared__ float part[4][Kq * D2];   // 28.8 KB

    if (tid < 64 * Kq / 2) {
        pr[tid]       = en[((size_t)b * Tq + tc * 64) * Kq + tid];
        pr[tid + 192] = en[((size_t)b * Tq + tc * 64) * Kq + tid + 192];
    }
    __syncthreads();

    const float* seqb = seq + (size_t)b * Tq * D2;

    float pp[Kq][5];
    #pragma unroll
    for (int k = 0; k < Kq; ++k)
        #pragma unroll
        for (int q = 0; q < 5; ++q) pp[k][q] = 0.f;

    for (int s = 0; s < 16; ++s) {
        const int tl = s * 4 + wv;
        const int tt = tc * 64 + tl;
        float prr[Kq];
        #pragma unroll
        for (int k = 0; k < Kq; ++k) prr[k] = pr[tl * Kq + k];
        #pragma unroll
        for (int q = 0; q < 5; ++q) {
            const int d = lane + q * 64;
            const float sv = (d < D2) ? seqb[(size_t)tt * D2 + d] : 0.f;
            #pragma unroll
            for (int k = 0; k < Kq; ++k) pp[k][q] += prr[k] * sv;
        }
    }
    #pragma unroll
    for (int k = 0; k < Kq; ++k)
        #pragma unroll
        for (int q = 0; q < 5; ++q) {
            const int d = lane + q * 64;
            if (d < D2) part[wv][k * D2 + d] = pp[k][q];
        }
    __syncthreads();
    float* op = partial + ((size_t)b * 8 + tc) * (Kq * D2);
    for (int o = tid; o < Kq * D2; o += 256)
        op[o] = part[0][o] + part[1][o] + part[2][o] + part[3][o];
}

// ---------------------------------------------------------------------------
// Kernel 4d: final: pooled reduce -> topic -> logits -> softmax.  grid (B)
// ---------------------------------------------------------------------------
__global__ __launch_bounds__(256) void final_kernel(
    const float* __restrict__ partial,
    const float* __restrict__ Wtop,
    const float* __restrict__ btop,
    const float* __restrict__ Wout,
    const float* __restrict__ bout,
    float* __restrict__ outp)
{
    const int b = blockIdx.x;
    const int tid = threadIdx.x;
    __shared__ float pooled[Kq * D2];
    __shared__ float feats[Kq * THq];
    __shared__ float lsm[8];

    for (int o = tid; o < Kq * D2; o += 256) {
        float s = 0.f;
        #pragma unroll
        for (int c = 0; c < 8; ++c)
            s += partial[((size_t)b * 8 + c) * (Kq * D2) + o];
        pooled[o] = s;
    }
    __syncthreads();

    if (tid < Kq * THq) {
        const int k = tid / THq, hh = tid % THq;
        float acc = btop[tid];
        const float* wp = Wtop + (size_t)k * D2 * THq + hh;
        for (int d = 0; d < D2; ++d)
            acc += pooled[k * D2 + d] * wp[(size_t)d * THq];
        feats[tid] = fmaxf(acc, 0.f);
    }
    __syncthreads();

    if (tid < CLSq) {
        float acc = bout[tid];
        for (int f = 0; f < Kq * THq; ++f)
            acc += feats[f] * Wout[f * CLSq + tid];
        lsm[tid] = acc;
    }
    __syncthreads();
    if (tid < CLSq) {
        float m = lsm[0];
        for (int c = 1; c < CLSq; ++c) m = fmaxf(m, lsm[c]);
        float s = 0.f;
        for (int c = 0; c < CLSq; ++c) s += __expf(lsm[c] - m);
        outp[(size_t)b * CLSq + tid] = __expf(lsm[tid] - m) / s;
    }
}

// ---------------------------------------------------------------------------
// Kernel 5: reg = mean_b regbuf[b]  -> d_out[640]
// ---------------------------------------------------------------------------
__global__ void reg_final(const float* __restrict__ regbuf, float* __restrict__ outp)
{
    const int tid = threadIdx.x;   // 128 threads
    float v = regbuf[tid];
    for (int off = 32; off > 0; off >>= 1) v += __shfl_xor(v, off, 64);
    __shared__ float r2[2];
    if ((tid & 63) == 0) r2[tid >> 6] = v;
    __syncthreads();
    if (tid == 0) outp[Bq * CLSq] = (r2[0] + r2[1]) * (1.f / (float)Bq);
}

// ---------------------------------------------------------------------------
extern "C" void kernel_launch(void* const* d_in, const int* in_sizes, int n_in,
                              void* d_out, int out_size, void* d_ws, size_t ws_size,
                              hipStream_t stream)
{
    const float* x     = (const float*)d_in[0];
    const float* Wih_f = (const float*)d_in[1];
    const float* Whh_f = (const float*)d_in[2];
    const float* bih_f = (const float*)d_in[3];
    const float* bhh_f = (const float*)d_in[4];
    const float* Wih_b = (const float*)d_in[5];
    const float* Whh_b = (const float*)d_in[6];
    const float* bih_b = (const float*)d_in[7];
    const float* bhh_b = (const float*)d_in[8];
    const float* attn_context = (const float*)d_in[9];
    const float* Wattn = (const float*)d_in[10];
    const float* battn = (const float*)d_in[11];
    const float* Wtop  = (const float*)d_in[12];
    const float* btop  = (const float*)d_in[13];
    const float* Wout  = (const float*)d_in[14];
    const float* bout  = (const float*)d_in[15];
    float* outp = (float*)d_out;

    // fixed workspace layout (float units)
    float* ws       = (float*)d_ws;
    float* seqv     = ws;                                   // 19,660,800
    float* hstate   = seqv + (size_t)Bq * Tq * D2;          // 38,400
    float* ctxW     = hstate + (size_t)2 * Bq * Hq;         // 1,800
    float* context  = ctxW + Kq * D2;                       // 230,400
    float* regbuf   = context + (size_t)Bq * Kq * D2;       // 128
    float* normsq   = regbuf + Bq;                          // 768
    float* en       = normsq + Bq * Kq;                     // 393,216
    float* partial  = en + (size_t)Bq * Tq * Kq;            // 1,843,200
    __hip_bfloat16* xb16 = (__hip_bfloat16*)(partial + (size_t)Bq * 8 * Kq * D2); // 19,660,800 bf16
    __hip_bfloat16* Wb16 = xb16 + (size_t)Bq * Tq * Iq;     // 270,000 bf16
    unsigned short* W16 = (unsigned short*)(Wb16 + (size_t)2 * G3 * Iq); // 136,800 f16
    float* gi_chunk = (float*)(W16 + (size_t)2 * G3 * 152); // 115200*TCr fp32
    const size_t fixed_floats = (size_t)(gi_chunk - ws);

    // pick largest TCr in {256,128,64,32} that fits ws_size
    int tcShift = 5;
    for (int sh = 8; sh >= 5; --sh) {
        size_t need = (fixed_floats + (size_t)115200 * (1 << sh)) * 4;
        if (need <= ws_size) { tcShift = sh; break; }
    }
    const int TCr = 1 << tcShift;
    const int NL = Tq / TCr;

    // one-time casts: x/Wih -> bf16 (MFMA gi), Whh -> f16 padded (LDS gemv)
    cast_bf16_kernel<<<dim3((Bq * Tq * Iq / 4 + 255) / 256), 256, 0, stream>>>(
        x, xb16, Bq * Tq * Iq / 4);
    cast_bf16_kernel<<<dim3((G3 * Iq / 4 + 255) / 256), 256, 0, stream>>>(
        Wih_f, Wb16, G3 * Iq / 4);
    cast_bf16_kernel<<<dim3((G3 * Iq / 4 + 255) / 256), 256, 0, stream>>>(
        Wih_b, Wb16 + (size_t)G3 * Iq, G3 * Iq / 4);
    cast_whh_f16<<<dim3((2 * G3 * 152 + 255) / 256), 256, 0, stream>>>(
        Whh_f, Whh_b, W16);

    for (int c = 0; c < NL; ++c) {
        const int t0f = c * TCr;
        const int t0b = Tq - TCr * (c + 1);
        gi_gemm_mfma<<<dim3(4, Bq * TCr / 128, 2), 256, 0, stream>>>(
            xb16, Wb16, bih_f, bih_b, gi_chunk, t0f, t0b, tcShift);
        gru_rec<<<dim3(2 * Bq), 512, 0, stream>>>(
            gi_chunk, W16, bhh_f, bhh_b, hstate, seqv, c, tcShift);
    }

    ctxw_kernel<<<dim3((Kq * D2 + 255) / 256), 256, 0, stream>>>(
        attn_context, Wattn, battn, ctxW);
    ctx_compute<<<dim3(Bq, Kq), 256, 0, stream>>>(seqv, Wattn, ctxW, context, normsq);
    gram_kernel<<<dim3(Bq), 256, 0, stream>>>(context, normsq, regbuf);
    energy_kernel<<<dim3(8, Bq), 256, 0, stream>>>(seqv, context, en);
    softmax_kernel<<<dim3(Bq), 256, 0, stream>>>(en);
    pooledp_kernel<<<dim3(8, Bq), 256, 0, stream>>>(seqv, en, partial);
    final_kernel<<<dim3(Bq), 256, 0, stream>>>(partial, Wtop, btop, Wout, bout, outp);
    reg_final<<<dim3(1), 128, 0, stream>>>(regbuf, outp);
}